// Round 2
// baseline (1823.657 us; speedup 1.0000x reference)
//
#include <hip/hip_runtime.h>
#include <math.h>

#define ALPHA_F 0.1f

// ---------------- edge format detection ----------------
// If edge_index arrives as int64 (little-endian), every odd 32-bit word of the
// first row is a zero high-word (values < 100000). If int32, those words are
// random source indices -> virtually impossible to all be zero.
__global__ __launch_bounds__(256) void k_detect(const int* __restrict__ ei, int E, int* __restrict__ flag) {
    __shared__ int anynz;
    if (threadIdx.x == 0) anynz = 0;
    __syncthreads();
    int bad = 0;
    for (int i = threadIdx.x; i < 4096; i += 256) {
        int idx = 2 * i + 1;
        if (idx < 2 * E) bad |= ei[idx];
    }
    if (bad) atomicOr(&anynz, 1);
    __syncthreads();
    if (threadIdx.x == 0) flag[0] = (anynz == 0) ? 1 : 0;  // 1 => int64 layout
}

__device__ __forceinline__ int edge_src(const int* ei, int e, int E, int is64) {
    return is64 ? ei[2 * e] : ei[e];
}
__device__ __forceinline__ int edge_dst(const int* ei, int e, int E, int is64) {
    return is64 ? ei[2 * E + 2 * e] : ei[E + e];
}

// ---------------- degree / CSR build ----------------
__global__ __launch_bounds__(256) void k_init(int* __restrict__ degi, int* __restrict__ cursor, int N) {
    int i = blockIdx.x * 256 + threadIdx.x;
    if (i < N) { degi[i] = 1; cursor[i] = 0; }  // deg includes the self-loop
}

__global__ __launch_bounds__(256) void k_count(const int* __restrict__ ei, const int* __restrict__ flag,
                                               int E, int* __restrict__ degi) {
    int e = blockIdx.x * 256 + threadIdx.x;
    if (e >= E) return;
    int is64 = flag[0];
    atomicAdd(&degi[edge_dst(ei, e, E, is64)], 1);
}

__global__ __launch_bounds__(256) void k_dinv(const int* __restrict__ degi, float* __restrict__ dinv, int N) {
    int i = blockIdx.x * 256 + threadIdx.x;
    if (i < N) dinv[i] = rsqrtf((float)degi[i]);  // deg >= 1 always
}

// exclusive scan of (degi[i]-1) over N+1 positions -> rowptr (CSR of real edges only)
__global__ __launch_bounds__(256) void k_scanA(const int* __restrict__ degi, int N, int* __restrict__ part) {
    __shared__ int sh[256];
    int i = blockIdx.x * 256 + threadIdx.x;
    int v = (i < N) ? degi[i] - 1 : 0;
    sh[threadIdx.x] = v;
    __syncthreads();
    for (int s = 128; s > 0; s >>= 1) {
        if (threadIdx.x < s) sh[threadIdx.x] += sh[threadIdx.x + s];
        __syncthreads();
    }
    if (threadIdx.x == 0) part[blockIdx.x] = sh[0];
}

__global__ __launch_bounds__(512) void k_scanB(int* __restrict__ part, int nb) {
    __shared__ int sh[512];
    int t = threadIdx.x;
    int v = (t < nb) ? part[t] : 0;
    sh[t] = v;
    __syncthreads();
    for (int off = 1; off < 512; off <<= 1) {
        int u = (t >= off) ? sh[t - off] : 0;
        __syncthreads();
        sh[t] += u;
        __syncthreads();
    }
    if (t < nb) part[t] = sh[t] - v;  // exclusive
}

__global__ __launch_bounds__(256) void k_scanC(const int* __restrict__ degi, int N,
                                               const int* __restrict__ part, int* __restrict__ rowptr) {
    __shared__ int sh[256];
    int t = threadIdx.x;
    int i = blockIdx.x * 256 + t;
    int v = (i < N) ? degi[i] - 1 : 0;
    sh[t] = v;
    __syncthreads();
    for (int off = 1; off < 256; off <<= 1) {
        int u = (t >= off) ? sh[t - off] : 0;
        __syncthreads();
        sh[t] += u;
        __syncthreads();
    }
    if (i <= N) rowptr[i] = sh[t] - v + part[blockIdx.x];
}

__global__ __launch_bounds__(256) void k_fill(const int* __restrict__ ei, const int* __restrict__ flag, int E,
                                              const int* __restrict__ rowptr, int* __restrict__ cursor,
                                              int* __restrict__ col) {
    int e = blockIdx.x * 256 + threadIdx.x;
    if (e >= E) return;
    int is64 = flag[0];
    int s = edge_src(ei, e, E, is64);
    int d = edge_dst(ei, e, E, is64);
    int p = rowptr[d] + atomicAdd(&cursor[d], 1);
    col[p] = s;
}

// ---------------- fused MLP: H0 = relu(x@W1 + b1) @ W2 + b2 ----------------
// Block: 64 rows x all 256 hidden cols. 256 threads, each an 8x8 fp32 tile.
// Epilogue applies W2 (LDS-resident, XOR-swizzled) + cross-lane reduce.
__global__ __launch_bounds__(256) void k_mlp(const float* __restrict__ x, const float* __restrict__ W1,
                                             const float* __restrict__ b1, const float* __restrict__ W2,
                                             const float* __restrict__ b2, float* __restrict__ H0, int N) {
    __shared__ float xs[16][64];     // transposed x tile
    __shared__ float w1s[16][256];
    __shared__ float4 w2s4[1024];    // W2 [256][16] as float4[256][4], quad-swizzled

    int t = threadIdx.x;
    int row0 = blockIdx.x * 64;

    // stage W2 with bank-spreading swizzle: quad q of row c stored at q ^ ((c>>3)&3)
    for (int i4 = t; i4 < 1024; i4 += 256) {
        int c = i4 >> 2, q = i4 & 3;
        w2s4[c * 4 + (q ^ ((c >> 3) & 3))] = ((const float4*)W2)[i4];
    }

    int tr = t >> 5, tc = t & 31;
    int tr8 = tr * 8, tc8 = tc * 8;

    float acc[8][8];
#pragma unroll
    for (int i = 0; i < 8; ++i)
#pragma unroll
        for (int j = 0; j < 8; ++j) acc[i][j] = 0.f;

    for (int kk = 0; kk < 512; kk += 16) {
        __syncthreads();
        {   // stage x tile (transposed): thread -> (row r, 4 consecutive k)
            int r = t >> 2, k4 = (t & 3) * 4;
            float4 v = make_float4(0.f, 0.f, 0.f, 0.f);
            int gr = row0 + r;
            if (gr < N) v = *(const float4*)(x + (size_t)gr * 512 + kk + k4);
            xs[k4 + 0][r] = v.x;
            xs[k4 + 1][r] = v.y;
            xs[k4 + 2][r] = v.z;
            xs[k4 + 3][r] = v.w;
        }
        {   // stage W1 rows kk..kk+15 (contiguous 16KB)
            const float4* w1g = (const float4*)(W1 + (size_t)kk * 256);
            float4* w1l = (float4*)&w1s[0][0];
#pragma unroll
            for (int j = 0; j < 4; ++j) w1l[t + j * 256] = w1g[t + j * 256];
        }
        __syncthreads();
#pragma unroll
        for (int k = 0; k < 16; ++k) {
            float a[8], b[8];
            *(float4*)&a[0] = *(float4*)&xs[k][tr8];
            *(float4*)&a[4] = *(float4*)&xs[k][tr8 + 4];
            *(float4*)&b[0] = *(float4*)&w1s[k][tc8];
            *(float4*)&b[4] = *(float4*)&w1s[k][tc8 + 4];
#pragma unroll
            for (int i = 0; i < 8; ++i)
#pragma unroll
                for (int j = 0; j < 8; ++j) acc[i][j] = fmaf(a[i], b[j], acc[i][j]);
        }
    }

    // epilogue: bias + relu + @W2 + cross-lane (tc) reduce
    float bias[8];
    *(float4*)&bias[0] = *(const float4*)(b1 + tc8);
    *(float4*)&bias[4] = *(const float4*)(b1 + tc8 + 4);
    float b2r[16];
#pragma unroll
    for (int q = 0; q < 4; ++q) *(float4*)&b2r[q * 4] = *(const float4*)(b2 + q * 4);

#pragma unroll
    for (int i = 0; i < 8; ++i) {
        float p[16];
#pragma unroll
        for (int o = 0; o < 16; ++o) p[o] = 0.f;
#pragma unroll
        for (int j = 0; j < 8; ++j) {
            float h = fmaxf(acc[i][j] + bias[j], 0.f);
            int c = tc8 + j;
            int sw = (c >> 3) & 3;
#pragma unroll
            for (int q = 0; q < 4; ++q) {
                float4 wv = w2s4[c * 4 + (q ^ sw)];
                p[q * 4 + 0] = fmaf(h, wv.x, p[q * 4 + 0]);
                p[q * 4 + 1] = fmaf(h, wv.y, p[q * 4 + 1]);
                p[q * 4 + 2] = fmaf(h, wv.z, p[q * 4 + 2]);
                p[q * 4 + 3] = fmaf(h, wv.w, p[q * 4 + 3]);
            }
        }
#pragma unroll
        for (int m = 1; m <= 16; m <<= 1)
#pragma unroll
            for (int o = 0; o < 16; ++o) p[o] += __shfl_xor(p[o], m, 64);
        if (tc == 0) {
            int gr = row0 + tr8 + i;
            if (gr < N) {
                float4* outp = (float4*)(H0 + (size_t)gr * 16);
                outp[0] = make_float4(p[0] + b2r[0], p[1] + b2r[1], p[2] + b2r[2], p[3] + b2r[3]);
                outp[1] = make_float4(p[4] + b2r[4], p[5] + b2r[5], p[6] + b2r[6], p[7] + b2r[7]);
                outp[2] = make_float4(p[8] + b2r[8], p[9] + b2r[9], p[10] + b2r[10], p[11] + b2r[11]);
                outp[3] = make_float4(p[12] + b2r[12], p[13] + b2r[13], p[14] + b2r[14], p[15] + b2r[15]);
            }
        }
    }
}

// ---------------- APPNP iteration: one wave per node ----------------
// lanes: sub = lane>>4 (edge subgroup 0..3), c = lane&15 (channel)
// h_new[d] = 0.9 * dinv[d] * (sum_e dinv[s]*h[s] + dinv[d]*h[d]) + 0.1 * h0[d]
__global__ __launch_bounds__(256) void k_prop(const float* __restrict__ hin, const float* __restrict__ h0,
                                              float* __restrict__ hout, const float* __restrict__ dinv,
                                              const int* __restrict__ rowptr, const int* __restrict__ col, int N) {
    int wid = (blockIdx.x * 256 + threadIdx.x) >> 6;
    if (wid >= N) return;
    int lane = threadIdx.x & 63;
    int sub = lane >> 4, c = lane & 15;
    int beg = rowptr[wid], end = rowptr[wid + 1];
    float acc = 0.f;
    for (int i = beg + sub; i < end; i += 4) {
        int s = col[i];
        acc = fmaf(dinv[s], hin[(size_t)s * 16 + c], acc);
    }
    acc += __shfl_xor(acc, 16, 64);
    acc += __shfl_xor(acc, 32, 64);
    if (sub == 0) {
        float di = dinv[wid];
        size_t base = (size_t)wid * 16 + c;
        hout[base] = 0.9f * di * (acc + di * hin[base]) + ALPHA_F * h0[base];
    }
}

// ---------------- log_softmax over 16 channels ----------------
__global__ __launch_bounds__(256) void k_lsm(const float* __restrict__ hin, float* __restrict__ out, int N) {
    int gid = blockIdx.x * 256 + threadIdx.x;
    int row = gid >> 4;
    if (row >= N) return;
    float v = hin[gid];
    float m = v;
#pragma unroll
    for (int mask = 1; mask <= 8; mask <<= 1) m = fmaxf(m, __shfl_xor(m, mask, 64));
    float e = __expf(v - m);
    float s = e;
#pragma unroll
    for (int mask = 1; mask <= 8; mask <<= 1) s += __shfl_xor(s, mask, 64);
    out[gid] = v - m - __logf(s);
}

extern "C" void kernel_launch(void* const* d_in, const int* in_sizes, int n_in,
                              void* d_out, int out_size, void* d_ws, size_t ws_size,
                              hipStream_t stream) {
    const float* x  = (const float*)d_in[0];
    const int*   ei = (const int*)d_in[1];
    const float* W1 = (const float*)d_in[2];
    const float* b1 = (const float*)d_in[3];
    const float* W2 = (const float*)d_in[4];
    const float* b2 = (const float*)d_in[5];
    float* out = (float*)d_out;

    int N = in_sizes[0] / 512;  // 100000
    int E = in_sizes[1] / 2;    // 3200000

    size_t off = 0;
    char* w = (char*)d_ws;
    auto alloc = [&](size_t bytes) -> void* {
        void* p = (void*)(w + off);
        off += (bytes + 511) & ~(size_t)511;
        return p;
    };
    int*   flag   = (int*)alloc(4);
    int*   degi   = (int*)alloc((size_t)N * 4);
    float* dinv   = (float*)alloc((size_t)N * 4);
    int*   rowptr = (int*)alloc((size_t)(N + 1) * 4);
    int*   cursor = (int*)alloc((size_t)N * 4);
    int*   part   = (int*)alloc(4096);
    int*   col    = (int*)alloc((size_t)E * 4);
    float* H0     = (float*)alloc((size_t)N * 16 * 4);
    float* HA     = (float*)alloc((size_t)N * 16 * 4);
    float* HB     = (float*)alloc((size_t)N * 16 * 4);
    (void)ws_size; (void)n_in; (void)out_size;

    int NB = (N + 256) / 256;                       // covers indices 0..N
    int EB = (E + 255) / 256;
    int MB = (N + 63) / 64;
    int PB = (int)(((size_t)N * 64 + 255) / 256);   // one wave per node
    int LB = (N * 16 + 255) / 256;

    k_detect<<<1, 256, 0, stream>>>(ei, E, flag);
    k_init<<<NB, 256, 0, stream>>>(degi, cursor, N);
    k_count<<<EB, 256, 0, stream>>>(ei, flag, E, degi);
    k_dinv<<<NB, 256, 0, stream>>>(degi, dinv, N);
    k_scanA<<<NB, 256, 0, stream>>>(degi, N, part);
    k_scanB<<<1, 512, 0, stream>>>(part, NB);
    k_scanC<<<NB, 256, 0, stream>>>(degi, N, part, rowptr);
    k_fill<<<EB, 256, 0, stream>>>(ei, flag, E, rowptr, cursor, col);
    k_mlp<<<MB, 256, 0, stream>>>(x, W1, b1, W2, b2, H0, N);

    const float* cur = H0;
    float* bufs[2] = {HA, HB};
    for (int k = 0; k < 10; ++k) {
        float* o2 = bufs[k & 1];
        k_prop<<<PB, 256, 0, stream>>>(cur, H0, o2, dinv, rowptr, col, N);
        cur = o2;
    }
    k_lsm<<<LB, 256, 0, stream>>>(cur, out, N);
}

// Round 3
// 1466.898 us; speedup vs baseline: 1.2432x; 1.2432x over previous
//
#include <hip/hip_runtime.h>
#include <math.h>

#define ALPHA_F 0.1f

typedef __attribute__((ext_vector_type(8))) short short8v;
typedef __attribute__((ext_vector_type(4))) float f32x4;

__device__ __forceinline__ unsigned short f2bf(float f) {
    union { float f; unsigned int u; } v; v.f = f;
    unsigned int u = v.u;
    u += 0x7fffu + ((u >> 16) & 1u);   // round-to-nearest-even
    return (unsigned short)(u >> 16);
}

// ---------------- edge format detection (int64 vs int32) ----------------
__global__ __launch_bounds__(256) void k_detect(const int* __restrict__ ei, int E, int* __restrict__ flag) {
    __shared__ int anynz;
    if (threadIdx.x == 0) anynz = 0;
    __syncthreads();
    int bad = 0;
    for (int i = threadIdx.x; i < 4096; i += 256) {
        int idx = 2 * i + 1;
        if (idx < 2 * E) bad |= ei[idx];
    }
    if (bad) atomicOr(&anynz, 1);
    __syncthreads();
    if (threadIdx.x == 0) flag[0] = (anynz == 0) ? 1 : 0;  // 1 => int64 layout
}

__device__ __forceinline__ int edge_src(const int* ei, int e, int E, int is64) {
    return is64 ? ei[2 * e] : ei[e];
}
__device__ __forceinline__ int edge_dst(const int* ei, int e, int E, int is64) {
    return is64 ? ei[2 * E + 2 * e] : ei[E + e];
}

// ---------------- degree / CSR build ----------------
__global__ __launch_bounds__(256) void k_init(int* __restrict__ degi, int* __restrict__ cursor, int N) {
    int i = blockIdx.x * 256 + threadIdx.x;
    if (i < N) { degi[i] = 1; cursor[i] = 0; }  // deg includes self-loop
}

__global__ __launch_bounds__(256) void k_count(const int* __restrict__ ei, const int* __restrict__ flag,
                                               int E, int* __restrict__ degi) {
    int e = blockIdx.x * 256 + threadIdx.x;
    if (e >= E) return;
    int is64 = flag[0];
    atomicAdd(&degi[edge_dst(ei, e, E, is64)], 1);
}

__global__ __launch_bounds__(256) void k_dinv(const int* __restrict__ degi, float* __restrict__ dinv, int N) {
    int i = blockIdx.x * 256 + threadIdx.x;
    if (i < N) dinv[i] = rsqrtf((float)degi[i]);
}

__global__ __launch_bounds__(256) void k_scanA(const int* __restrict__ degi, int N, int* __restrict__ part) {
    __shared__ int sh[256];
    int i = blockIdx.x * 256 + threadIdx.x;
    int v = (i < N) ? degi[i] - 1 : 0;
    sh[threadIdx.x] = v;
    __syncthreads();
    for (int s = 128; s > 0; s >>= 1) {
        if (threadIdx.x < s) sh[threadIdx.x] += sh[threadIdx.x + s];
        __syncthreads();
    }
    if (threadIdx.x == 0) part[blockIdx.x] = sh[0];
}

__global__ __launch_bounds__(512) void k_scanB(int* __restrict__ part, int nb) {
    __shared__ int sh[512];
    int t = threadIdx.x;
    int v = (t < nb) ? part[t] : 0;
    sh[t] = v;
    __syncthreads();
    for (int off = 1; off < 512; off <<= 1) {
        int u = (t >= off) ? sh[t - off] : 0;
        __syncthreads();
        sh[t] += u;
        __syncthreads();
    }
    if (t < nb) part[t] = sh[t] - v;  // exclusive
}

__global__ __launch_bounds__(256) void k_scanC(const int* __restrict__ degi, int N,
                                               const int* __restrict__ part, int* __restrict__ rowptr) {
    __shared__ int sh[256];
    int t = threadIdx.x;
    int i = blockIdx.x * 256 + t;
    int v = (i < N) ? degi[i] - 1 : 0;
    sh[t] = v;
    __syncthreads();
    for (int off = 1; off < 256; off <<= 1) {
        int u = (t >= off) ? sh[t - off] : 0;
        __syncthreads();
        sh[t] += u;
        __syncthreads();
    }
    if (i <= N) rowptr[i] = sh[t] - v + part[blockIdx.x];
}

__global__ __launch_bounds__(256) void k_fill(const int* __restrict__ ei, const int* __restrict__ flag, int E,
                                              const int* __restrict__ rowptr, int* __restrict__ cursor,
                                              int* __restrict__ col) {
    int e = blockIdx.x * 256 + threadIdx.x;
    if (e >= E) return;
    int is64 = flag[0];
    int s = edge_src(ei, e, E, is64);
    int d = edge_dst(ei, e, E, is64);
    int p = rowptr[d] + atomicAdd(&cursor[d], 1);
    col[p] = s;
}

// ---------------- weight prep: transpose + fp32->bf16 ----------------
// W1 [512][256] f32 -> w1t [256][512] bf16 (n-major, k contiguous)
__global__ __launch_bounds__(256) void k_w1prep(const float* __restrict__ W1, unsigned short* __restrict__ w1t) {
    __shared__ float tile[64][65];
    int t = threadIdx.x;
    int k0 = (blockIdx.x >> 2) * 64, n0 = (blockIdx.x & 3) * 64;
#pragma unroll
    for (int i = 0; i < 4; ++i) {
        int r = (t >> 4) + 16 * i;       // k row within tile
        int c4 = (t & 15) * 4;
        float4 v = *(const float4*)(W1 + (size_t)(k0 + r) * 256 + n0 + c4);
        tile[r][c4 + 0] = v.x; tile[r][c4 + 1] = v.y;
        tile[r][c4 + 2] = v.z; tile[r][c4 + 3] = v.w;
    }
    __syncthreads();
#pragma unroll
    for (int i = 0; i < 4; ++i) {
        int nrow = (t >> 4) + 16 * i;    // n within tile
        int k4 = (t & 15) * 4;
        ushort4 o;
        o.x = f2bf(tile[k4 + 0][nrow]); o.y = f2bf(tile[k4 + 1][nrow]);
        o.z = f2bf(tile[k4 + 2][nrow]); o.w = f2bf(tile[k4 + 3][nrow]);
        *(ushort4*)(w1t + (size_t)(n0 + nrow) * 512 + k0 + k4) = o;
    }
}

// W2 [256][16] f32 -> w2t [16][256] bf16
__global__ __launch_bounds__(256) void k_w2prep(const float* __restrict__ W2, unsigned short* __restrict__ w2t) {
    int t = threadIdx.x;
    int c = t & 15, k16 = (t >> 4) * 16;
    unsigned short tmp[16];
#pragma unroll
    for (int j = 0; j < 16; ++j) tmp[j] = f2bf(W2[(size_t)(k16 + j) * 16 + c]);
#pragma unroll
    for (int j = 0; j < 16; ++j) w2t[(size_t)c * 256 + k16 + j] = tmp[j];
}

// ---------------- MFMA MLP: H0 = relu(x@W1+b1)@W2+b2 ; G0 = dinv*H0 ----------------
// 64 rows/block, 4 waves; wave w owns hidden-slice [64w,64w+64).
// LDS phase1: xs [64][128B] + w1s [256][128B] (XOR-swizzled rows), phase2: h1s [64][512B].
__global__ __launch_bounds__(256, 3) void k_mlp(const float* __restrict__ x,
        const unsigned short* __restrict__ w1t, const float* __restrict__ b1,
        const unsigned short* __restrict__ w2t, const float* __restrict__ b2,
        const float* __restrict__ dinv, float* __restrict__ H0, float* __restrict__ G0, int N) {
    __shared__ __align__(16) char lds[40960];
    char* xs  = lds;              // [64 rows][128 B]
    char* w1s = lds + 8 * 1024;   // [256 rows][128 B]
    char* h1s = lds;              // [64 rows][512 B]   (phase 2, aliases xs/w1s)

    int t = threadIdx.x;
    int w = t >> 6, l = t & 63;
    int row0 = blockIdx.x * 64;

    f32x4 acc[4][4];
#pragma unroll
    for (int i = 0; i < 4; ++i)
#pragma unroll
        for (int j = 0; j < 4; ++j) acc[i][j] = (f32x4){0.f, 0.f, 0.f, 0.f};

    for (int c = 0; c < 8; ++c) {
        int k0 = c * 64;
        __syncthreads();
        {   // stage xs: row r, 16 consecutive k; convert fp32->bf16
            int r = t >> 2, c16 = (t & 3) * 16;
            int gr = row0 + r;
            float vf[16];
            if (gr < N) {
                const float* xp = x + (size_t)gr * 512 + k0 + c16;
#pragma unroll
                for (int q = 0; q < 4; ++q) *(float4*)&vf[q * 4] = *(const float4*)(xp + q * 4);
            } else {
#pragma unroll
                for (int q = 0; q < 16; ++q) vf[q] = 0.f;
            }
            union { unsigned short u[8]; short8v v; } p0, p1;
#pragma unroll
            for (int j = 0; j < 8; ++j) { p0.u[j] = f2bf(vf[j]); p1.u[j] = f2bf(vf[8 + j]); }
            int sw = (r & 7) << 4;
            *(short8v*)(xs + r * 128 + ((2 * c16) ^ sw)) = p0.v;
            *(short8v*)(xs + r * 128 + ((2 * c16 + 16) ^ sw)) = p1.v;
        }
        {   // stage w1s: slot s=(n,oct); LDS linear in s, global pre-swizzled
#pragma unroll
            for (int i = 0; i < 8; ++i) {
                int s = t + 256 * i;          // 0..2047
                int n = s >> 3, oct = s & 7;
                const unsigned short* gp = w1t + (size_t)n * 512 + k0 + 8 * (oct ^ (n & 7));
                *(short8v*)(w1s + s * 16) = *(const short8v*)gp;
            }
        }
        __syncthreads();
#pragma unroll
        for (int ks = 0; ks < 2; ++ks) {
            int kb = ks * 64 + 16 * (l >> 4);
            short8v af[4], bfr[4];
#pragma unroll
            for (int mf = 0; mf < 4; ++mf) {
                int m = 16 * mf + (l & 15);
                af[mf] = *(const short8v*)(xs + m * 128 + (kb ^ ((m & 7) << 4)));
            }
#pragma unroll
            for (int nt = 0; nt < 4; ++nt) {
                int n = 64 * w + 16 * nt + (l & 15);
                bfr[nt] = *(const short8v*)(w1s + n * 128 + (kb ^ ((n & 7) << 4)));
            }
#pragma unroll
            for (int mf = 0; mf < 4; ++mf)
#pragma unroll
                for (int nt = 0; nt < 4; ++nt)
                    acc[mf][nt] = __builtin_amdgcn_mfma_f32_16x16x32_bf16(af[mf], bfr[nt], acc[mf][nt], 0, 0, 0);
        }
    }

    // bias + relu -> h1s (bf16)
    __syncthreads();
    float b1v[4];
#pragma unroll
    for (int nt = 0; nt < 4; ++nt) b1v[nt] = b1[64 * w + 16 * nt + (l & 15)];
#pragma unroll
    for (int mf = 0; mf < 4; ++mf)
#pragma unroll
        for (int nt = 0; nt < 4; ++nt)
#pragma unroll
            for (int r = 0; r < 4; ++r) {
                int m = 16 * mf + 4 * (l >> 4) + r;
                int n = 64 * w + 16 * nt + (l & 15);
                float val = fmaxf(acc[mf][nt][r] + b1v[nt], 0.f);
                *(unsigned short*)(h1s + m * 512 + ((2 * n) ^ ((m & 7) << 4))) = f2bf(val);
            }
    __syncthreads();

    // GEMM2: wave w computes rows 16w..16w+15, all 16 out cols, K=256
    f32x4 a2 = (f32x4){0.f, 0.f, 0.f, 0.f};
#pragma unroll
    for (int k2 = 0; k2 < 256; k2 += 32) {
        int kb = 2 * k2 + 16 * (l >> 4);
        int m = 16 * w + (l & 15);
        short8v am = *(const short8v*)(h1s + m * 512 + (kb ^ ((m & 7) << 4)));
        short8v bm = *(const short8v*)(w2t + (size_t)(l & 15) * 256 + k2 + 8 * (l >> 4));
        a2 = __builtin_amdgcn_mfma_f32_16x16x32_bf16(am, bm, a2, 0, 0, 0);
    }
    float b2v = b2[l & 15];
#pragma unroll
    for (int r = 0; r < 4; ++r) {
        int m = 16 * w + 4 * (l >> 4) + r;
        int gr = row0 + m;
        if (gr < N) {
            float hv = a2[r] + b2v;
            size_t idx = (size_t)gr * 16 + (l & 15);
            H0[idx] = hv;
            G0[idx] = dinv[gr] * hv;
        }
    }
}

// ---------------- APPNP iteration on pre-scaled buffers ----------------
// g = dinv*h.  h_new[d] = 0.9*dinv[d]*(sum_e g[s] + g[d]) + 0.1*h0[d]
// out = last ? h_new : dinv[d]*h_new
__global__ __launch_bounds__(256) void k_prop(const float* __restrict__ gin, const float* __restrict__ h0,
                                              float* __restrict__ outb, const float* __restrict__ dinv,
                                              const int* __restrict__ rowptr, const int* __restrict__ col,
                                              int N, int last) {
    int wid = (blockIdx.x * 256 + threadIdx.x) >> 6;
    if (wid >= N) return;
    int lane = threadIdx.x & 63;
    int sub = lane >> 4, c = lane & 15;
    int beg = rowptr[wid], end = rowptr[wid + 1];
    float acc = 0.f;
    for (int i = beg + sub; i < end; i += 4) {
        int s = col[i];
        acc += gin[(size_t)s * 16 + c];
    }
    acc += __shfl_xor(acc, 16, 64);
    acc += __shfl_xor(acc, 32, 64);
    if (sub == 0) {
        float di = dinv[wid];
        size_t base = (size_t)wid * 16 + c;
        float hnew = 0.9f * di * (acc + gin[base]) + ALPHA_F * h0[base];
        outb[base] = last ? hnew : di * hnew;
    }
}

// ---------------- log_softmax over 16 channels ----------------
__global__ __launch_bounds__(256) void k_lsm(const float* __restrict__ hin, float* __restrict__ out, int N) {
    int gid = blockIdx.x * 256 + threadIdx.x;
    int row = gid >> 4;
    if (row >= N) return;
    float v = hin[gid];
    float m = v;
#pragma unroll
    for (int mask = 1; mask <= 8; mask <<= 1) m = fmaxf(m, __shfl_xor(m, mask, 64));
    float e = __expf(v - m);
    float s = e;
#pragma unroll
    for (int mask = 1; mask <= 8; mask <<= 1) s += __shfl_xor(s, mask, 64);
    out[gid] = v - m - __logf(s);
}

extern "C" void kernel_launch(void* const* d_in, const int* in_sizes, int n_in,
                              void* d_out, int out_size, void* d_ws, size_t ws_size,
                              hipStream_t stream) {
    const float* x  = (const float*)d_in[0];
    const int*   ei = (const int*)d_in[1];
    const float* W1 = (const float*)d_in[2];
    const float* b1 = (const float*)d_in[3];
    const float* W2 = (const float*)d_in[4];
    const float* b2 = (const float*)d_in[5];
    float* out = (float*)d_out;

    int N = in_sizes[0] / 512;  // 100000
    int E = in_sizes[1] / 2;    // 3200000

    size_t off = 0;
    char* w = (char*)d_ws;
    auto alloc = [&](size_t bytes) -> void* {
        void* p = (void*)(w + off);
        off += (bytes + 511) & ~(size_t)511;
        return p;
    };
    int*    flag   = (int*)alloc(4);
    int*    degi   = (int*)alloc((size_t)N * 4);
    float*  dinv   = (float*)alloc((size_t)N * 4);
    int*    rowptr = (int*)alloc((size_t)(N + 1) * 4);
    int*    cursor = (int*)alloc((size_t)N * 4);
    int*    part   = (int*)alloc(4096);
    int*    col    = (int*)alloc((size_t)E * 4);
    float*  H0     = (float*)alloc((size_t)N * 16 * 4);
    float*  GA     = (float*)alloc((size_t)N * 16 * 4);
    float*  GB     = (float*)alloc((size_t)N * 16 * 4);
    unsigned short* w1t = (unsigned short*)alloc((size_t)512 * 256 * 2);
    unsigned short* w2t = (unsigned short*)alloc((size_t)256 * 16 * 2);
    (void)ws_size; (void)n_in; (void)out_size;

    int NB = (N + 256) / 256;
    int EB = (E + 255) / 256;
    int MB = (N + 63) / 64;
    int PB = (int)(((size_t)N * 64 + 255) / 256);
    int LB = (N * 16 + 255) / 256;

    k_detect<<<1, 256, 0, stream>>>(ei, E, flag);
    k_init<<<NB, 256, 0, stream>>>(degi, cursor, N);
    k_count<<<EB, 256, 0, stream>>>(ei, flag, E, degi);
    k_dinv<<<NB, 256, 0, stream>>>(degi, dinv, N);
    k_scanA<<<NB, 256, 0, stream>>>(degi, N, part);
    k_scanB<<<1, 512, 0, stream>>>(part, NB);
    k_scanC<<<NB, 256, 0, stream>>>(degi, N, part, rowptr);
    k_fill<<<EB, 256, 0, stream>>>(ei, flag, E, rowptr, cursor, col);

    k_w1prep<<<32, 256, 0, stream>>>(W1, w1t);
    k_w2prep<<<1, 256, 0, stream>>>(W2, w2t);
    k_mlp<<<MB, 256, 0, stream>>>(x, w1t, b1, w2t, b2, dinv, H0, GA, N);

    // g-buffers: even k: GA->GB, odd k: GB->GA; k=9 (odd) writes unscaled h into GA
    const float* cur = GA;
    for (int k = 0; k < 10; ++k) {
        float* o2 = (k & 1) ? GA : GB;
        k_prop<<<PB, 256, 0, stream>>>(cur, H0, o2, dinv, rowptr, col, N, (k == 9) ? 1 : 0);
        cur = o2;
    }
    k_lsm<<<LB, 256, 0, stream>>>(GA, out, N);
}